// Round 6
// baseline (28583.154 us; speedup 1.0000x reference)
//
#include <hip/hip_runtime.h>

#define KK 67
#define DIN 4
#define CLIPM 16
#define NEPOCH 5

typedef float float2v __attribute__((ext_vector_type(2)));

__device__ __forceinline__ float ex2(float x) {
#if __has_builtin(__builtin_amdgcn_exp2f)
    return __builtin_amdgcn_exp2f(x);
#else
    return exp2f(x);
#endif
}
__device__ __forceinline__ float frcp(float x) {
#if __has_builtin(__builtin_amdgcn_rcpf)
    return __builtin_amdgcn_rcpf(x);
#else
    return 1.0f / x;
#endif
}

// VOP3P packed FMA. All sources are VGPR pairs. Broadcast one half of the
// x-pair to both result lanes via op_sel / op_sel_hi.
__device__ __forceinline__ void pkfma_lo(float2v& acc, float2v x, float2v w) {
    asm("v_pk_fma_f32 %0, %1, %2, %0 op_sel:[0,0,0] op_sel_hi:[0,1,1]"
        : "+v"(acc) : "v"(x), "v"(w));
}
__device__ __forceinline__ void pkfma_hi(float2v& acc, float2v x, float2v w) {
    asm("v_pk_fma_f32 %0, %1, %2, %0 op_sel:[1,0,0] op_sel_hi:[1,1,1]"
        : "+v"(acc) : "v"(x), "v"(w));
}

// DPP lane shuffles (VALU pipe). 0xB1=quad xor1, 0x4E=quad xor2,
// 0x141=row_half_mirror (xor7 within 8-lane half-row).
template<int CTRL>
__device__ __forceinline__ float dppf(float v) {
    return __int_as_float(__builtin_amdgcn_mov_dpp(__float_as_int(v), CTRL, 0xF, 0xF, false));
}
__device__ __forceinline__ float bperm(int byteaddr, float v) {
    return __int_as_float(__builtin_amdgcn_ds_bpermute(byteaddr, __float_as_int(v)));
}

// ---------------- Phase 1: per-frame GRNN + projections (parallel over T) ----------------
__global__ __launch_bounds__(128) void grnn_kernel(
    const float* __restrict__ vid,
    const float* __restrict__ W1, const float* __restrict__ b1,
    const float* __restrict__ gw, const float* __restrict__ gb,
    const float* __restrict__ gWih, const float* __restrict__ gWhh,
    const float* __restrict__ gbih, const float* __restrict__ gbhh,
    const float* __restrict__ W2, const float* __restrict__ b2,
    float* __restrict__ q)
{
    const int f = blockIdx.x;
    const int t = threadIdx.x;
    const int k = t;
    __shared__ float sWih[256], sWhh[256], sb[32], sW1[32], sb1[8], sW2[64], sb2[8];
    __shared__ float Msum[8];
    for (int i = t; i < 256; i += 128) { sWih[i] = gWih[i]; sWhh[i] = gWhh[i]; }
    if (t < 32) sb[t] = gbih[t] + gbhh[t];
    if (t < 32) sW1[t] = W1[t];
    if (t < 8)  sb1[t] = b1[t];
    if (t < 64) sW2[t] = W2[t];
    if (t < 8)  sb2[t] = b2[t];
    __syncthreads();

    const bool act = (k < KK);
    float R[8], S[8], gwl[8], gbl[8];
    if (act) {
        const float* vp = vid + ((size_t)f * KK + k) * DIN;
        const float v0 = vp[0], v1 = vp[1], v2 = vp[2], v3 = vp[3];
#pragma unroll
        for (int j = 0; j < 8; ++j) {
            R[j] = sb1[j] + sW1[j*4+0]*v0 + sW1[j*4+1]*v1 + sW1[j*4+2]*v2 + sW1[j*4+3]*v3;
            S[j] = 0.0f;
            gwl[j] = gw[k*8 + j];
            gbl[j] = gb[k*8 + j];
        }
    }
    for (int e = 0; e < NEPOCH; ++e) {
        if (t < 8) Msum[t] = 0.0f;
        __syncthreads();
        float per[8];
        if (act) {
#pragma unroll
            for (int j = 0; j < 8; ++j) { per[j] = gwl[j]*S[j] + gbl[j]; atomicAdd(&Msum[j], per[j]); }
        }
        __syncthreads();
        if (act) {
            float M[8];
#pragma unroll
            for (int j = 0; j < 8; ++j) M[j] = Msum[j] - per[j];
            float gv[32];
#pragma unroll
            for (int gg = 0; gg < 32; ++gg) {
                float a = sb[gg];
#pragma unroll
                for (int j = 0; j < 8; ++j)
                    a = fmaf(R[j], sWih[gg*8+j], fmaf(M[j], sWhh[gg*8+j], a));
                gv[gg] = a;
            }
#pragma unroll
            for (int j = 0; j < 8; ++j) {
                float sg_i = frcp(1.f + ex2(-1.4426950408889634f * gv[j]));
                float sg_f = frcp(1.f + ex2(-1.4426950408889634f * gv[8+j]));
                float th_g = 1.f - 2.f * frcp(1.f + ex2(2.8853900817779268f * gv[16+j]));
                float sg_o = frcp(1.f + ex2(-1.4426950408889634f * gv[24+j]));
                float c2 = sg_f * S[j] + sg_i * th_g;
                float h2 = sg_o * (1.f - 2.f * frcp(1.f + ex2(2.8853900817779268f * c2)));
                R[j] += S[j];   // updateRelation uses OLD lastS
                S[j] = h2;
            }
        }
        __syncthreads();
    }
    if (act) {
        float* qp = q + ((size_t)f * KK + k) * 8;
#pragma unroll
        for (int jo = 0; jo < 8; ++jo) {
            float a = sb2[jo];
#pragma unroll
            for (int j = 0; j < 8; ++j) a = fmaf(fmaxf(R[j], 0.0f), sW2[jo*8+j], a);
            qp[jo] = a;
        }
    }
}

// ---------------- Phase 2: slope-4 superstep wavefront ----------------
// At superstep D, layer l (lane group l) processes positions 4(D-l)..4(D-l)+3
// back-to-back. Exchange (4 ds_bpermute), x-side gate sums, staging and ring
// loads are paid once per 4 positions; only the ~100cy cell chain is serial.
__global__ void
__attribute__((amdgpu_flat_work_group_size(64, 64), amdgpu_waves_per_eu(1, 1)))
slstm_kernel(
    const float* __restrict__ q,
    const float* __restrict__ pWih, const float* __restrict__ pWhh,
    const float* __restrict__ pbih, const float* __restrict__ pbhh,
    const float* __restrict__ vWih, const float* __restrict__ vWhh,
    const float* __restrict__ vbih, const float* __restrict__ vbhh,
    float* __restrict__ out, int U, int N)
{
    const int lane = threadIdx.x;
    const int l = lane >> 3, s = lane & 7;
    const int isV = blockIdx.x;
    const float* Wih = isV ? vWih : pWih;
    const float* Whh = isV ? vWhh : pWhh;
    const float* bi  = isV ? vbih : pbih;
    const float* bh  = isV ? vbhh : pbhh;
    float* ob = out + (size_t)isV * (size_t)N * 64;

    const float cS = -1.4426950408889634f;   // -log2(e): sigmoid rows
    const float cT =  2.8853900817779268f;   // 2*log2(e): tanh row

    // Gather slot k holds element j = s ^ M[k] (DPP butterfly order).
    const int M[8] = {0, 1, 2, 3, 7, 6, 5, 4};

    float2v wih01[8], wih23[8], whh01[8], whh23[8], b01, b23;
    {
        const int r_i = l*32 + 0*8 + s, r_f = l*32 + 1*8 + s;
        const int r_g = l*32 + 2*8 + s, r_o = l*32 + 3*8 + s;
#pragma unroll
        for (int kk = 0; kk < 8; ++kk) {
            const int j = s ^ M[kk];
            wih01[kk] = float2v{cS * Wih[r_i*8+j], cS * Wih[r_f*8+j]};
            wih23[kk] = float2v{cT * Wih[r_g*8+j], cS * Wih[r_o*8+j]};
            whh01[kk] = float2v{cS * Whh[r_i*8+j], cS * Whh[r_f*8+j]};
            whh23[kk] = float2v{cT * Whh[r_g*8+j], cS * Whh[r_o*8+j]};
        }
        b01 = float2v{cS*(bi[r_i]+bh[r_i]), cS*(bi[r_f]+bh[r_f])};
        b23 = float2v{cT*(bi[r_g]+bh[r_g]), cS*(bi[r_o]+bh[r_o])};
    }

    const int axo = ((lane + 56) & 63) << 2;   // pull from lane-8 (group l-1)

    float hp = 0.f, c = 0.f, cs = 0.f, Hm = 0.f, Hc = 0.f;
    const bool g7 = (l == 7);
    const float vsel = isV ? 1.0f : 0.0f;
    const int maxu = U - 1;

    // staged quad: g7 lanes hold q-inputs for next superstep; others hold y
    float ys0 = g7 ? q[0*8+s] : 0.f;
    float ys1 = g7 ? q[1*8+s] : 0.f;
    float ys2 = g7 ? q[2*8+s] : 0.f;
    float ys3 = g7 ? q[3*8+s] : 0.f;

    // x-side: DPP all-gather + 16 pkfma (bias included) -> gate pre-sums
    auto xsum = [&](float xi, float2v& a01o, float2v& a23o) {
        const float xA = dppf<0xB1>(xi);
        const float xB = dppf<0x4E>(xi);
        const float xC = dppf<0x4E>(xA);
        const float xD = dppf<0x141>(xi);
        const float xE = dppf<0x141>(xA);
        const float xF = dppf<0x141>(xB);
        const float xG = dppf<0x141>(xC);
        const float2v p0 = {xi, xA}, p1 = {xB, xC}, p2 = {xD, xE}, p3 = {xF, xG};
        float2v a01 = b01, a23 = b23;
        float2v u01 = {0.f, 0.f}, u23 = {0.f, 0.f};
        pkfma_lo(a01, p0, wih01[0]); pkfma_hi(a01, p0, wih01[1]);
        pkfma_lo(a23, p0, wih23[0]); pkfma_hi(a23, p0, wih23[1]);
        pkfma_lo(a01, p1, wih01[2]); pkfma_hi(a01, p1, wih01[3]);
        pkfma_lo(a23, p1, wih23[2]); pkfma_hi(a23, p1, wih23[3]);
        pkfma_lo(u01, p2, wih01[4]); pkfma_hi(u01, p2, wih01[5]);
        pkfma_lo(u23, p2, wih23[4]); pkfma_hi(u23, p2, wih23[5]);
        pkfma_lo(u01, p3, wih01[6]); pkfma_hi(u01, p3, wih01[7]);
        pkfma_lo(u23, p3, wih23[6]); pkfma_hi(u23, p3, wih23[7]);
        a01o = a01 + u01;
        a23o = a23 + u23;
    };

    // one LSTM cell given pre-summed x gates; hcur/ccur/cscur in, outputs
    auto cell = [&](float2v xa01, float2v xa23, float hcur, float ccur, float cscur,
                    float& h2o, float& c2o, float& cso) {
        const float hA = dppf<0xB1>(hcur);
        const float hB = dppf<0x4E>(hcur);
        const float hC = dppf<0x4E>(hA);
        const float hD = dppf<0x141>(hcur);
        const float hE = dppf<0x141>(hA);
        const float hF = dppf<0x141>(hB);
        const float hG = dppf<0x141>(hC);
        const float2v h0 = {hcur, hA}, h1 = {hB, hC}, h2v = {hD, hE}, h3 = {hF, hG};
        float2v g01 = {0.f, 0.f}, g23 = {0.f, 0.f};
        float2v u01 = {0.f, 0.f}, u23 = {0.f, 0.f};
        pkfma_lo(g01, h0, whh01[0]); pkfma_hi(g01, h0, whh01[1]);
        pkfma_lo(g23, h0, whh23[0]); pkfma_hi(g23, h0, whh23[1]);
        pkfma_lo(g01, h1, whh01[2]); pkfma_hi(g01, h1, whh01[3]);
        pkfma_lo(g23, h1, whh23[2]); pkfma_hi(g23, h1, whh23[3]);
        pkfma_lo(u01, h2v, whh01[4]); pkfma_hi(u01, h2v, whh01[5]);
        pkfma_lo(u23, h2v, whh23[4]); pkfma_hi(u23, h2v, whh23[5]);
        pkfma_lo(u01, h3, whh01[6]); pkfma_hi(u01, h3, whh01[7]);
        pkfma_lo(u23, h3, whh23[6]); pkfma_hi(u23, h3, whh23[7]);
        const float2v a01 = (xa01 + g01) + u01;
        const float2v a23 = (xa23 + g23) + u23;
        const float ig = frcp(1.f + ex2(a01.x));
        const float fg = frcp(1.f + ex2(a01.y));
        const float rg = frcp(1.f + ex2(a23.x));
        const float og = frcp(1.f + ex2(a23.y));
        const float gt  = fmaf(-2.f, rg, 1.f);
        const float gtT = fmaf(-2.f*cT, rg, cT);
        c2o = fmaf(fg, ccur, ig * gt);
        cso = fmaf(fg, cscur, ig * gtT);
        const float th = fmaf(-2.f, frcp(1.f + ex2(cso)), 1.f);
        h2o = og * th;
    };

    // ---- startup supersteps D = 0..6: direct staged loads, group l active iff l <= D ----
    for (int D = 0; D < 7; ++D) {
        const float x0 = bperm(axo, ys0), x1 = bperm(axo, ys1);
        const float x2 = bperm(axo, ys2), x3 = bperm(axo, ys3);
        float2v a010, a230, a011, a231, a012, a232, a013, a233;
        xsum(x0, a010, a230); xsum(x1, a011, a231);
        xsum(x2, a012, a232); xsum(x3, a013, a233);
        const bool act = (l <= D);
        float h2, c2, cs2;
        cell(a010, a230, hp, c, cs, h2, c2, cs2);
        float hr = act ? h2 : hp; float cr = act ? c2 : c; float csr = act ? cs2 : cs;
        const float y0 = h2 + x0;
        cell(a011, a231, hr, cr, csr, h2, c2, cs2);
        hr = act ? h2 : hr; cr = act ? c2 : cr; csr = act ? cs2 : csr;
        const float y1 = h2 + x1;
        cell(a012, a232, hr, cr, csr, h2, c2, cs2);
        hr = act ? h2 : hr; cr = act ? c2 : cr; csr = act ? cs2 : csr;
        const float y2 = h2 + x2;
        cell(a013, a233, hr, cr, csr, h2, c2, cs2);
        hp = act ? h2 : hr; c = act ? c2 : cr; cs = act ? cs2 : csr;
        const float y3 = h2 + x3;
        const int ub = 4*(D+1);   // staged positions (< 36 < KK: no V-subtract)
        ys0 = g7 ? q[(ub+0)*8+s] : y0;
        ys1 = g7 ? q[(ub+1)*8+s] : y1;
        ys2 = g7 ? q[(ub+2)*8+s] : y2;
        ys3 = g7 ? q[(ub+3)*8+s] : y3;
    }

    // ---- prefetch ring: 16 slots = 4 supersteps deep; slot group (D-7)&3 ----
    float ra[16], rb[16];
#pragma unroll
    for (int p = 0; p < 16; ++p) {
        int u = 32 + p; if (u > maxu) u = maxu;
        ra[p] = q[u*8 + s];
        int ubb = u - KK; if (ubb < 0) ubb = 0;
        rb[p] = q[ubb*8 + s];
    }

    int ubase = 32;   // staged-quad base position for the current superstep

    // one superstep: sb = static ring slot base; boundary => dlt valid
    auto sstep = [&](int sb, bool boundary, int dlt, bool lastk, int kclip) {
        const float x0 = bperm(axo, ys0), x1 = bperm(axo, ys1);
        const float x2 = bperm(axo, ys2), x3 = bperm(axo, ys3);
        float2v a010, a230, a011, a231, a012, a232, a013, a233;
        xsum(x0, a010, a230); xsum(x1, a011, a231);
        xsum(x2, a012, a232); xsum(x3, a013, a233);
        float h2, c2, cs2;
        if (!boundary) {
            cell(a010, a230, hp, c, cs, h2, c2, cs2);
            const float y0 = h2 + x0; float hr = h2, cr = c2, csr = cs2;
            cell(a011, a231, hr, cr, csr, h2, c2, cs2);
            const float y1 = h2 + x1; hr = h2; cr = c2; csr = cs2;
            cell(a012, a232, hr, cr, csr, h2, c2, cs2);
            const float y2 = h2 + x2; hr = h2; cr = c2; csr = cs2;
            cell(a013, a233, hr, cr, csr, h2, c2, cs2);
            const float y3 = h2 + x3;
            hp = h2; c = c2; cs = cs2;
            // staging + ring refill
            const float qb0 = (ubase+0 >= KK) ? rb[sb+0] : 0.f;
            const float qb1 = (ubase+1 >= KK) ? rb[sb+1] : 0.f;
            const float qb2 = (ubase+2 >= KK) ? rb[sb+2] : 0.f;
            const float qb3 = (ubase+3 >= KK) ? rb[sb+3] : 0.f;
            ys0 = g7 ? fmaf(-vsel, qb0, ra[sb+0]) : y0;
            ys1 = g7 ? fmaf(-vsel, qb1, ra[sb+1]) : y1;
            ys2 = g7 ? fmaf(-vsel, qb2, ra[sb+2]) : y2;
            ys3 = g7 ? fmaf(-vsel, qb3, ra[sb+3]) : y3;
        } else {
            const bool act = (!lastk) || (l >= dlt);
            cell(a010, a230, hp, c, cs, h2, c2, cs2);
            const float y0 = h2 + x0;
            float hr = act ? h2 : hp; float cr = act ? c2 : c; float csr = act ? cs2 : cs;
            cell(a011, a231, hr, cr, csr, h2, c2, cs2);
            const float y1 = h2 + x1;
            hr = act ? h2 : hr; cr = act ? c2 : cr; csr = act ? cs2 : csr;
            cell(a012, a232, hr, cr, csr, h2, c2, cs2);
            const float y2 = h2 + x2;
            hr = act ? h2 : hr; cr = act ? c2 : cr; csr = act ? cs2 : csr;
            cell(a013, a233, hr, cr, csr, h2, c2, cs2);
            const float y3 = h2 + x3;
            // clip reset for group dlt at sub-position 3
            const bool bnd = (l == dlt);
            const float HmN = Hm + h2, HcN = Hc + c2;
            const float hpN = bnd ? HmN : h2;
            const float cN  = bnd ? HcN : c2;
            const float csN = bnd ? cT * HcN : cs2;
            hp = act ? hpN : hr; c = act ? cN : cr; cs = act ? csN : csr;
            Hm = bnd ? HmN : Hm;
            Hc = bnd ? HcN : Hc;
            if (bnd) ob[(size_t)kclip * 64 + lane] = HmN;
            const float qb0 = (ubase+0 >= KK) ? rb[sb+0] : 0.f;
            const float qb1 = (ubase+1 >= KK) ? rb[sb+1] : 0.f;
            const float qb2 = (ubase+2 >= KK) ? rb[sb+2] : 0.f;
            const float qb3 = (ubase+3 >= KK) ? rb[sb+3] : 0.f;
            ys0 = g7 ? fmaf(-vsel, qb0, ra[sb+0]) : y0;
            ys1 = g7 ? fmaf(-vsel, qb1, ra[sb+1]) : y1;
            ys2 = g7 ? fmaf(-vsel, qb2, ra[sb+2]) : y2;
            ys3 = g7 ? fmaf(-vsel, qb3, ra[sb+3]) : y3;
        }
        // ring refill: u' = ubase + i + 16 (consumed 4 supersteps later)
#pragma unroll
        for (int i = 0; i < 4; ++i) {
            int ua = ubase + i + 16; if (ua > maxu) ua = maxu;
            ra[sb+i] = q[ua*8 + s];
            int ubb = ua - KK; if (ubb < 0) ubb = 0;
            rb[sb+i] = q[ubb*8 + s];
        }
        ubase += 4;
    };

    for (int k = 0; k < N; ++k) {
        const bool lastk = (k == N - 1);
        for (int it = 0; it < 65; ++it) {
            sstep(0,  false, 0, false, k);
            sstep(4,  false, 0, false, k);
            sstep(8,  false, 0, false, k);
            sstep(12, false, 0, false, k);
        }
#pragma unroll
        for (int i2 = 0; i2 < 4; ++i2) sstep(i2*4, true, i2,     lastk, k);
#pragma unroll
        for (int i2 = 0; i2 < 4; ++i2) sstep(i2*4, true, 4 + i2, lastk, k);
    }
}

extern "C" void kernel_launch(void* const* d_in, const int* in_sizes, int n_in,
                              void* d_out, int out_size, void* d_ws, size_t ws_size,
                              hipStream_t stream)
{
    const float* vid  = (const float*)d_in[0];
    const float* W1   = (const float*)d_in[1];
    const float* b1   = (const float*)d_in[2];
    const float* gw   = (const float*)d_in[3];
    const float* gb   = (const float*)d_in[4];
    const float* gWih = (const float*)d_in[5];
    const float* gWhh = (const float*)d_in[6];
    const float* gbih = (const float*)d_in[7];
    const float* gbhh = (const float*)d_in[8];
    const float* W2   = (const float*)d_in[9];
    const float* b2   = (const float*)d_in[10];
    const float* vWih = (const float*)d_in[11];
    const float* vWhh = (const float*)d_in[12];
    const float* vbih = (const float*)d_in[13];
    const float* vbhh = (const float*)d_in[14];
    const float* pWih = (const float*)d_in[15];
    const float* pWhh = (const float*)d_in[16];
    const float* pbih = (const float*)d_in[17];
    const float* pbhh = (const float*)d_in[18];

    const int T = in_sizes[0] / (KK * DIN);
    const int N = T / CLIPM;
    const int U = N * CLIPM * KK;
    float* q = (float*)d_ws;   // T*KK*8 floats = 4.4 MB

    grnn_kernel<<<dim3(T), dim3(128), 0, stream>>>(
        vid, W1, b1, gw, gb, gWih, gWhh, gbih, gbhh, W2, b2, q);
    slstm_kernel<<<dim3(2), dim3(64), 0, stream>>>(
        q, pWih, pWhh, pbih, pbhh, vWih, vWhh, vbih, vbhh, (float*)d_out, U, N);
}

// Round 9
// 26695.938 us; speedup vs baseline: 1.0707x; 1.0707x over previous
//
#include <hip/hip_runtime.h>

#define KK 67
#define DIN 4
#define CLIPM 16
#define NEPOCH 5

typedef float float2v __attribute__((ext_vector_type(2)));
typedef _Float16 half2v __attribute__((ext_vector_type(2)));

__device__ __forceinline__ float ex2(float x) {
#if __has_builtin(__builtin_amdgcn_exp2f)
    return __builtin_amdgcn_exp2f(x);
#else
    return exp2f(x);
#endif
}
__device__ __forceinline__ float frcp(float x) {
#if __has_builtin(__builtin_amdgcn_rcpf)
    return __builtin_amdgcn_rcpf(x);
#else
    return 1.0f / x;
#endif
}
__device__ __forceinline__ half2v pkrtz(float a, float b) {
    return __builtin_bit_cast(half2v, __builtin_amdgcn_cvt_pkrtz(a, b));
}

// VOP3P packed f16 FMA, full-rate. Broadcast lo/hi half of the value pair to
// both result halves; weights supply per-gate halves; acc stays per-half.
__device__ __forceinline__ void pkfma16_lo(half2v& acc, half2v x, half2v w) {
    asm("v_pk_fma_f16 %0, %1, %2, %0 op_sel:[0,0,0] op_sel_hi:[0,1,1]"
        : "+v"(acc) : "v"(x), "v"(w));
}
__device__ __forceinline__ void pkfma16_hi(half2v& acc, half2v x, half2v w) {
    asm("v_pk_fma_f16 %0, %1, %2, %0 op_sel:[1,0,0] op_sel_hi:[1,1,1]"
        : "+v"(acc) : "v"(x), "v"(w));
}

// DPP lane shuffles (VALU pipe). 0xB1=quad xor1, 0x4E=quad xor2,
// 0x141=row_half_mirror (xor7 within 8-lane half-row).
template<int CTRL>
__device__ __forceinline__ float dppf(float v) {
    return __int_as_float(__builtin_amdgcn_mov_dpp(__float_as_int(v), CTRL, 0xF, 0xF, false));
}
__device__ __forceinline__ float bperm(int byteaddr, float v) {
    return __int_as_float(__builtin_amdgcn_ds_bpermute(byteaddr, __float_as_int(v)));
}

// ---------------- Phase 1: per-frame GRNN + projections (parallel over T) ----------------
__global__ __launch_bounds__(128) void grnn_kernel(
    const float* __restrict__ vid,
    const float* __restrict__ W1, const float* __restrict__ b1,
    const float* __restrict__ gw, const float* __restrict__ gb,
    const float* __restrict__ gWih, const float* __restrict__ gWhh,
    const float* __restrict__ gbih, const float* __restrict__ gbhh,
    const float* __restrict__ W2, const float* __restrict__ b2,
    float* __restrict__ q)
{
    const int f = blockIdx.x;
    const int t = threadIdx.x;
    const int k = t;
    __shared__ float sWih[256], sWhh[256], sb[32], sW1[32], sb1[8], sW2[64], sb2[8];
    __shared__ float Msum[8];
    for (int i = t; i < 256; i += 128) { sWih[i] = gWih[i]; sWhh[i] = gWhh[i]; }
    if (t < 32) sb[t] = gbih[t] + gbhh[t];
    if (t < 32) sW1[t] = W1[t];
    if (t < 8)  sb1[t] = b1[t];
    if (t < 64) sW2[t] = W2[t];
    if (t < 8)  sb2[t] = b2[t];
    __syncthreads();

    const bool act = (k < KK);
    float R[8], S[8], gwl[8], gbl[8];
    if (act) {
        const float* vp = vid + ((size_t)f * KK + k) * DIN;
        const float v0 = vp[0], v1 = vp[1], v2 = vp[2], v3 = vp[3];
#pragma unroll
        for (int j = 0; j < 8; ++j) {
            R[j] = sb1[j] + sW1[j*4+0]*v0 + sW1[j*4+1]*v1 + sW1[j*4+2]*v2 + sW1[j*4+3]*v3;
            S[j] = 0.0f;
            gwl[j] = gw[k*8 + j];
            gbl[j] = gb[k*8 + j];
        }
    }
    for (int e = 0; e < NEPOCH; ++e) {
        if (t < 8) Msum[t] = 0.0f;
        __syncthreads();
        float per[8];
        if (act) {
#pragma unroll
            for (int j = 0; j < 8; ++j) { per[j] = gwl[j]*S[j] + gbl[j]; atomicAdd(&Msum[j], per[j]); }
        }
        __syncthreads();
        if (act) {
            float M[8];
#pragma unroll
            for (int j = 0; j < 8; ++j) M[j] = Msum[j] - per[j];
            float gv[32];
#pragma unroll
            for (int gg = 0; gg < 32; ++gg) {
                float a = sb[gg];
#pragma unroll
                for (int j = 0; j < 8; ++j)
                    a = fmaf(R[j], sWih[gg*8+j], fmaf(M[j], sWhh[gg*8+j], a));
                gv[gg] = a;
            }
#pragma unroll
            for (int j = 0; j < 8; ++j) {
                float sg_i = frcp(1.f + ex2(-1.4426950408889634f * gv[j]));
                float sg_f = frcp(1.f + ex2(-1.4426950408889634f * gv[8+j]));
                float th_g = 1.f - 2.f * frcp(1.f + ex2(2.8853900817779268f * gv[16+j]));
                float sg_o = frcp(1.f + ex2(-1.4426950408889634f * gv[24+j]));
                float c2 = sg_f * S[j] + sg_i * th_g;
                float h2 = sg_o * (1.f - 2.f * frcp(1.f + ex2(2.8853900817779268f * c2)));
                R[j] += S[j];   // updateRelation uses OLD lastS
                S[j] = h2;
            }
        }
        __syncthreads();
    }
    if (act) {
        float* qp = q + ((size_t)f * KK + k) * 8;
#pragma unroll
        for (int jo = 0; jo < 8; ++jo) {
            float a = sb2[jo];
#pragma unroll
            for (int j = 0; j < 8; ++j) a = fmaf(fmaxf(R[j], 0.0f), sW2[jo*8+j], a);
            qp[jo] = a;
        }
    }
}

// ---------------- Phase 2: slope-4 superstep wavefront, f16 packed matvecs ----------------
__global__ void
__attribute__((amdgpu_flat_work_group_size(64, 64), amdgpu_waves_per_eu(1, 1)))
slstm_kernel(
    const float* __restrict__ q,
    const float* __restrict__ pWih, const float* __restrict__ pWhh,
    const float* __restrict__ pbih, const float* __restrict__ pbhh,
    const float* __restrict__ vWih, const float* __restrict__ vWhh,
    const float* __restrict__ vbih, const float* __restrict__ vbhh,
    float* __restrict__ out, int U, int N)
{
    const int lane = threadIdx.x;
    const int l = lane >> 3, s = lane & 7;
    const int isV = blockIdx.x;
    const float* Wih = isV ? vWih : pWih;
    const float* Whh = isV ? vWhh : pWhh;
    const float* bi  = isV ? vbih : pbih;
    const float* bh  = isV ? vbhh : pbhh;
    float* ob = out + (size_t)isV * (size_t)N * 64;

    const float cS = -1.4426950408889634f;   // -log2(e): sigmoid rows (i,f,o)
    const float cT =  2.8853900817779268f;   // 2*log2(e): tanh row (g)
    const float invcT = 0.34657359027997264f;

    // DPP butterfly gather order: slot n holds element j = s ^ M[n]
    const int M[8] = {0, 1, 2, 3, 7, 6, 5, 4};

    // f16-packed weights: index n in [0,8) = butterfly slot; pair = {gate_lo, gate_hi}
    half2v wih01[8], wih23[8], whh01[8], whh23[8], b01, b23;
    {
        const int r_i = l*32 + 0*8 + s, r_f = l*32 + 1*8 + s;
        const int r_g = l*32 + 2*8 + s, r_o = l*32 + 3*8 + s;
#pragma unroll
        for (int n = 0; n < 8; ++n) {
            const int j = s ^ M[n];
            wih01[n] = half2v{(_Float16)(cS * Wih[r_i*8+j]), (_Float16)(cS * Wih[r_f*8+j])};
            wih23[n] = half2v{(_Float16)(cT * Wih[r_g*8+j]), (_Float16)(cS * Wih[r_o*8+j])};
            whh01[n] = half2v{(_Float16)(cS * Whh[r_i*8+j]), (_Float16)(cS * Whh[r_f*8+j])};
            whh23[n] = half2v{(_Float16)(cT * Whh[r_g*8+j]), (_Float16)(cS * Whh[r_o*8+j])};
        }
        b01 = half2v{(_Float16)(cS*(bi[r_i]+bh[r_i])), (_Float16)(cS*(bi[r_f]+bh[r_f]))};
        b23 = half2v{(_Float16)(cT*(bi[r_g]+bh[r_g])), (_Float16)(cS*(bi[r_o]+bh[r_o]))};
    }

    const int axo = ((lane + 56) & 63) << 2;   // pull from lane-8 (group l-1)

    float hp = 0.f, cs = 0.f, Hm = 0.f, Hc = 0.f;   // cs = cT * cell-state
    const bool g7 = (l == 7);
    const float vsel = isV ? 1.0f : 0.0f;

    // x-side: DPP all-gather of an f32 value, pack to f16 pairs, 16 pk_fma_f16
    auto xsum = [&](float xi, half2v& a01o, half2v& a23o) {
        const float xA = dppf<0xB1>(xi);
        const float xB = dppf<0x4E>(xi);
        const float xC = dppf<0x4E>(xA);
        const float xD = dppf<0x141>(xi);
        const float xE = dppf<0x141>(xA);
        const float xF = dppf<0x141>(xB);
        const float xG = dppf<0x141>(xC);
        const half2v p0 = pkrtz(xi, xA), p1 = pkrtz(xB, xC);
        const half2v p2 = pkrtz(xD, xE), p3 = pkrtz(xF, xG);
        half2v a01 = b01, a23 = b23;
        pkfma16_lo(a01, p0, wih01[0]); pkfma16_hi(a01, p0, wih01[1]);
        pkfma16_lo(a23, p0, wih23[0]); pkfma16_hi(a23, p0, wih23[1]);
        pkfma16_lo(a01, p1, wih01[2]); pkfma16_hi(a01, p1, wih01[3]);
        pkfma16_lo(a23, p1, wih23[2]); pkfma16_hi(a23, p1, wih23[3]);
        pkfma16_lo(a01, p2, wih01[4]); pkfma16_hi(a01, p2, wih01[5]);
        pkfma16_lo(a23, p2, wih23[4]); pkfma16_hi(a23, p2, wih23[5]);
        pkfma16_lo(a01, p3, wih01[6]); pkfma16_hi(a01, p3, wih01[7]);
        pkfma16_lo(a23, p3, wih23[6]); pkfma16_hi(a23, p3, wih23[7]);
        a01o = a01; a23o = a23;
    };

    // cell: h-gather + h-side pk_fma_f16 seeded with x-side sums.
    // Inf-safety: clamp the two ex2 inputs that feed (E-1)*rcp products
    // (Eg, Ec); all other overflow paths resolve to frcp(inf)=0 times a
    // finite factor. Without the clamps, Eg=inf or Ec=inf -> inf*0 = NaN.
    auto cell = [&](half2v xa01, half2v xa23, float hcur, float cscur,
                    float& h2o, float& cso) {
        const float hA = dppf<0xB1>(hcur);
        const float hB = dppf<0x4E>(hcur);
        const float hC = dppf<0x4E>(hA);
        const float hD = dppf<0x141>(hcur);
        const float hE = dppf<0x141>(hA);
        const float hF = dppf<0x141>(hB);
        const float hG = dppf<0x141>(hC);
        const half2v p0 = pkrtz(hcur, hA), p1 = pkrtz(hB, hC);
        const half2v p2 = pkrtz(hD, hE), p3 = pkrtz(hF, hG);
        half2v a01 = xa01, a23 = xa23;
        pkfma16_lo(a01, p0, whh01[0]); pkfma16_hi(a01, p0, whh01[1]);
        pkfma16_lo(a23, p0, whh23[0]); pkfma16_hi(a23, p0, whh23[1]);
        pkfma16_lo(a01, p1, whh01[2]); pkfma16_hi(a01, p1, whh01[3]);
        pkfma16_lo(a23, p1, whh23[2]); pkfma16_hi(a23, p1, whh23[3]);
        pkfma16_lo(a01, p2, whh01[4]); pkfma16_hi(a01, p2, whh01[5]);
        pkfma16_lo(a23, p2, whh23[4]); pkfma16_hi(a23, p2, whh23[5]);
        pkfma16_lo(a01, p3, whh01[6]); pkfma16_hi(a01, p3, whh01[7]);
        pkfma16_lo(a23, p3, whh23[6]); pkfma16_hi(a23, p3, whh23[7]);
        const float Ei = ex2((float)a01.x);
        const float Ef = ex2((float)a01.y);
        const float Eg = ex2(fminf((float)a23.x, 96.f));
        const float Eo = ex2((float)a23.y);
        const float fg = frcp(1.f + Ef);
        const float ri = frcp((1.f + Ei) * (1.f + Eg));
        const float igtT = fmaf(cT, Eg, -cT) * ri;     // cT*ig*tanh(g)
        const float cs2 = fmaf(fg, cscur, igtT);
        const float Ec = ex2(fminf(cs2, 96.f));
        const float rh = frcp((1.f + Ec) * (1.f + Eo));
        h2o = (Ec - 1.f) * rh;                          // og * tanh(c)
        cso = cs2;
    };

    // staged inputs (g7 lanes: q-derived; others: y) + pipelined bperm results
    float ys0 = g7 ? q[0*8+s] : 0.f;
    float ys1 = g7 ? q[1*8+s] : 0.f;
    float ys2 = g7 ? q[2*8+s] : 0.f;
    float ys3 = g7 ? q[3*8+s] : 0.f;
    float xq0 = bperm(axo, ys0), xq1 = bperm(axo, ys1);
    float xq2 = bperm(axo, ys2), xq3 = bperm(axo, ys3);

    // ---- startup supersteps D = 0..6 ----
    for (int D = 0; D < 7; ++D) {
        half2v a010, a230, a011, a231, a012, a232, a013, a233;
        xsum(xq0, a010, a230); xsum(xq1, a011, a231);
        xsum(xq2, a012, a232); xsum(xq3, a013, a233);
        const bool act = (l <= D);
        float h2, cs2;
        cell(a010, a230, hp, cs, h2, cs2);
        float hr = act ? h2 : hp; float csr = act ? cs2 : cs;
        const float y0 = h2 + xq0;
        cell(a011, a231, hr, csr, h2, cs2);
        hr = act ? h2 : hr; csr = act ? cs2 : csr;
        const float y1 = h2 + xq1;
        cell(a012, a232, hr, csr, h2, cs2);
        hr = act ? h2 : hr; csr = act ? cs2 : csr;
        const float y2 = h2 + xq2;
        cell(a013, a233, hr, csr, h2, cs2);
        hp = act ? h2 : hr; cs = act ? cs2 : csr;
        const float y3 = h2 + xq3;
        const int ub = 4*(D+1);   // positions 4..31 < KK: no V subtract
        ys0 = g7 ? q[(ub+0)*8+s] : y0;
        ys1 = g7 ? q[(ub+1)*8+s] : y1;
        ys2 = g7 ? q[(ub+2)*8+s] : y2;
        ys3 = g7 ? q[(ub+3)*8+s] : y3;
        xq0 = bperm(axo, ys0); xq1 = bperm(axo, ys1);
        xq2 = bperm(axo, ys2); xq3 = bperm(axo, ys3);
    }

    // ---- prefetch ring: 16 slots = 4 supersteps deep; scalar-index loads ----
    float ra[16], rb[16];
#pragma unroll
    for (int p = 0; p < 16; ++p) {
        const int u = 32 + p;                 // 32..47, all valid
        ra[p] = q[u*8 + s];
        int ubb = u - KK; if (ubb < 0) ubb = 0;
        rb[p] = q[ubb*8 + s];
    }

    int upos = 32;            // consume base position (uniform scalar)
    const int Um4 = U - 4;

    auto sstep = [&](int sb, bool boundary, int dlt, bool lastk, int kclip) {
        half2v a010, a230, a011, a231, a012, a232, a013, a233;
        xsum(xq0, a010, a230); xsum(xq1, a011, a231);
        xsum(xq2, a012, a232); xsum(xq3, a013, a233);
        float h2, cs2;
        float y0, y1, y2, y3;
        if (!boundary) {
            cell(a010, a230, hp, cs, h2, cs2);
            y0 = h2 + xq0;
            cell(a011, a231, h2, cs2, h2, cs2);
            y1 = h2 + xq1;
            cell(a012, a232, h2, cs2, h2, cs2);
            y2 = h2 + xq2;
            cell(a013, a233, h2, cs2, h2, cs2);
            y3 = h2 + xq3;
            hp = h2; cs = cs2;
        } else {
            const bool act = (!lastk) || (l >= dlt);
            cell(a010, a230, hp, cs, h2, cs2);
            y0 = h2 + xq0;
            float hr = act ? h2 : hp; float csr = act ? cs2 : cs;
            cell(a011, a231, hr, csr, h2, cs2);
            y1 = h2 + xq1;
            hr = act ? h2 : hr; csr = act ? cs2 : csr;
            cell(a012, a232, hr, csr, h2, cs2);
            y2 = h2 + xq2;
            hr = act ? h2 : hr; csr = act ? cs2 : csr;
            cell(a013, a233, hr, csr, h2, cs2);
            y3 = h2 + xq3;
            const bool bnd = (l == dlt);
            const float HmN = Hm + h2;
            const float HcN = Hc + cs2 * invcT;
            const float hpN = bnd ? HmN : h2;
            const float csN = bnd ? cT * HcN : cs2;
            hp = act ? hpN : hr; cs = act ? csN : csr;
            Hm = bnd ? HmN : Hm;
            Hc = bnd ? HcN : Hc;
            if (bnd) ob[(size_t)kclip * 64 + lane] = HmN;
        }
        // staging from ring (consume-time masks are uniform -> SALU)
        const float qb0 = (upos+0 >= KK) ? rb[sb+0] : 0.f;
        const float qb1 = (upos+1 >= KK) ? rb[sb+1] : 0.f;
        const float qb2 = (upos+2 >= KK) ? rb[sb+2] : 0.f;
        const float qb3 = (upos+3 >= KK) ? rb[sb+3] : 0.f;
        ys0 = g7 ? fmaf(-vsel, qb0, ra[sb+0]) : y0;
        ys1 = g7 ? fmaf(-vsel, qb1, ra[sb+1]) : y1;
        ys2 = g7 ? fmaf(-vsel, qb2, ra[sb+2]) : y2;
        ys3 = g7 ? fmaf(-vsel, qb3, ra[sb+3]) : y3;
        xq0 = bperm(axo, ys0); xq1 = bperm(axo, ys1);
        xq2 = bperm(axo, ys2); xq3 = bperm(axo, ys3);
        // ring refill: scalar-clamped base indices, imm-offset loads
        int ur = upos + 16; if (ur > Um4) ur = Um4;
        int urb = ur - KK;  if (urb < 0) urb = 0;
        const float* pa = q + ur*8 + s;
        const float* pb = q + urb*8 + s;
        ra[sb+0] = pa[0];  ra[sb+1] = pa[8];  ra[sb+2] = pa[16]; ra[sb+3] = pa[24];
        rb[sb+0] = pb[0];  rb[sb+1] = pb[8];  rb[sb+2] = pb[16]; rb[sb+3] = pb[24];
        upos += 4;
    };

    for (int k = 0; k < N; ++k) {
        const bool lastk = (k == N - 1);
        for (int it = 0; it < 65; ++it) {
            sstep(0,  false, 0, false, k);
            sstep(4,  false, 0, false, k);
            sstep(8,  false, 0, false, k);
            sstep(12, false, 0, false, k);
        }
#pragma unroll
        for (int i2 = 0; i2 < 4; ++i2) sstep(i2*4, true, i2,     lastk, k);
#pragma unroll
        for (int i2 = 0; i2 < 4; ++i2) sstep(i2*4, true, 4 + i2, lastk, k);
    }
}

extern "C" void kernel_launch(void* const* d_in, const int* in_sizes, int n_in,
                              void* d_out, int out_size, void* d_ws, size_t ws_size,
                              hipStream_t stream)
{
    const float* vid  = (const float*)d_in[0];
    const float* W1   = (const float*)d_in[1];
    const float* b1   = (const float*)d_in[2];
    const float* gw   = (const float*)d_in[3];
    const float* gb   = (const float*)d_in[4];
    const float* gWih = (const float*)d_in[5];
    const float* gWhh = (const float*)d_in[6];
    const float* gbih = (const float*)d_in[7];
    const float* gbhh = (const float*)d_in[8];
    const float* W2   = (const float*)d_in[9];
    const float* b2   = (const float*)d_in[10];
    const float* vWih = (const float*)d_in[11];
    const float* vWhh = (const float*)d_in[12];
    const float* vbih = (const float*)d_in[13];
    const float* vbhh = (const float*)d_in[14];
    const float* pWih = (const float*)d_in[15];
    const float* pWhh = (const float*)d_in[16];
    const float* pbih = (const float*)d_in[17];
    const float* pbhh = (const float*)d_in[18];

    const int T = in_sizes[0] / (KK * DIN);
    const int N = T / CLIPM;
    const int U = N * CLIPM * KK;
    float* q = (float*)d_ws;   // T*KK*8 floats = 4.4 MB

    grnn_kernel<<<dim3(T), dim3(128), 0, stream>>>(
        vid, W1, b1, gw, gb, gWih, gWhh, gbih, gbhh, W2, b2, q);
    slstm_kernel<<<dim3(2), dim3(64), 0, stream>>>(
        q, pWih, pWhh, pbih, pbhh, vWih, vWhh, vbih, vbhh, (float*)d_out, U, N);
}

// Round 10
// 23082.716 us; speedup vs baseline: 1.2383x; 1.1565x over previous
//
#include <hip/hip_runtime.h>

#define KK 67
#define DIN 4
#define CLIPM 16
#define NEPOCH 5

typedef _Float16 half2v __attribute__((ext_vector_type(2)));
typedef __fp16  fp16v2 __attribute__((ext_vector_type(2)));

__device__ __forceinline__ float ex2(float x) {
#if __has_builtin(__builtin_amdgcn_exp2f)
    return __builtin_amdgcn_exp2f(x);
#else
    return exp2f(x);
#endif
}
__device__ __forceinline__ float frcp(float x) {
#if __has_builtin(__builtin_amdgcn_rcpf)
    return __builtin_amdgcn_rcpf(x);
#else
    return 1.0f / x;
#endif
}
__device__ __forceinline__ half2v pkrtz(float a, float b) {
    return __builtin_bit_cast(half2v, __builtin_amdgcn_cvt_pkrtz(a, b));
}
// v_dot2_f32_f16: d = a.lo*b.lo + a.hi*b.hi + c  (f32 accumulate, full-rate VOP3P)
__device__ __forceinline__ float fdot2(float a_bits, half2v b, float c) {
#if __has_builtin(__builtin_amdgcn_fdot2)
    return __builtin_amdgcn_fdot2(__builtin_bit_cast(fp16v2, a_bits),
                                  __builtin_bit_cast(fp16v2, b), c, false);
#else
    half2v a = __builtin_bit_cast(half2v, a_bits);
    return (float)a.x * (float)b.x + (float)a.y * (float)b.y + c;
#endif
}

// DPP lane shuffles (VALU pipe). 0xB1=quad xor1, 0x4E=quad xor2,
// 0x141=row_half_mirror (xor7 within 8-lane half-row).
template<int CTRL>
__device__ __forceinline__ float dppf(float v) {
    return __int_as_float(__builtin_amdgcn_mov_dpp(__float_as_int(v), CTRL, 0xF, 0xF, false));
}
__device__ __forceinline__ float bperm(int byteaddr, float v) {
    return __int_as_float(__builtin_amdgcn_ds_bpermute(byteaddr, __float_as_int(v)));
}

// ---------------- Phase 1: per-frame GRNN + projections (parallel over T) ----------------
__global__ __launch_bounds__(128) void grnn_kernel(
    const float* __restrict__ vid,
    const float* __restrict__ W1, const float* __restrict__ b1,
    const float* __restrict__ gw, const float* __restrict__ gb,
    const float* __restrict__ gWih, const float* __restrict__ gWhh,
    const float* __restrict__ gbih, const float* __restrict__ gbhh,
    const float* __restrict__ W2, const float* __restrict__ b2,
    float* __restrict__ q)
{
    const int f = blockIdx.x;
    const int t = threadIdx.x;
    const int k = t;
    __shared__ float sWih[256], sWhh[256], sb[32], sW1[32], sb1[8], sW2[64], sb2[8];
    __shared__ float Msum[8];
    for (int i = t; i < 256; i += 128) { sWih[i] = gWih[i]; sWhh[i] = gWhh[i]; }
    if (t < 32) sb[t] = gbih[t] + gbhh[t];
    if (t < 32) sW1[t] = W1[t];
    if (t < 8)  sb1[t] = b1[t];
    if (t < 64) sW2[t] = W2[t];
    if (t < 8)  sb2[t] = b2[t];
    __syncthreads();

    const bool act = (k < KK);
    float R[8], S[8], gwl[8], gbl[8];
    if (act) {
        const float* vp = vid + ((size_t)f * KK + k) * DIN;
        const float v0 = vp[0], v1 = vp[1], v2 = vp[2], v3 = vp[3];
#pragma unroll
        for (int j = 0; j < 8; ++j) {
            R[j] = sb1[j] + sW1[j*4+0]*v0 + sW1[j*4+1]*v1 + sW1[j*4+2]*v2 + sW1[j*4+3]*v3;
            S[j] = 0.0f;
            gwl[j] = gw[k*8 + j];
            gbl[j] = gb[k*8 + j];
        }
    }
    for (int e = 0; e < NEPOCH; ++e) {
        if (t < 8) Msum[t] = 0.0f;
        __syncthreads();
        float per[8];
        if (act) {
#pragma unroll
            for (int j = 0; j < 8; ++j) { per[j] = gwl[j]*S[j] + gbl[j]; atomicAdd(&Msum[j], per[j]); }
        }
        __syncthreads();
        if (act) {
            float M[8];
#pragma unroll
            for (int j = 0; j < 8; ++j) M[j] = Msum[j] - per[j];
            float gv[32];
#pragma unroll
            for (int gg = 0; gg < 32; ++gg) {
                float a = sb[gg];
#pragma unroll
                for (int j = 0; j < 8; ++j)
                    a = fmaf(R[j], sWih[gg*8+j], fmaf(M[j], sWhh[gg*8+j], a));
                gv[gg] = a;
            }
#pragma unroll
            for (int j = 0; j < 8; ++j) {
                float sg_i = frcp(1.f + ex2(-1.4426950408889634f * gv[j]));
                float sg_f = frcp(1.f + ex2(-1.4426950408889634f * gv[8+j]));
                float th_g = 1.f - 2.f * frcp(1.f + ex2(2.8853900817779268f * gv[16+j]));
                float sg_o = frcp(1.f + ex2(-1.4426950408889634f * gv[24+j]));
                float c2 = sg_f * S[j] + sg_i * th_g;
                float h2 = sg_o * (1.f - 2.f * frcp(1.f + ex2(2.8853900817779268f * c2)));
                R[j] += S[j];   // updateRelation uses OLD lastS
                S[j] = h2;
            }
        }
        __syncthreads();
    }
    if (act) {
        float* qp = q + ((size_t)f * KK + k) * 8;
#pragma unroll
        for (int jo = 0; jo < 8; ++jo) {
            float a = sb2[jo];
#pragma unroll
            for (int j = 0; j < 8; ++j) a = fmaf(fmaxf(R[j], 0.0f), sW2[jo*8+j], a);
            qp[jo] = a;
        }
    }
}

// ---------------- Phase 2: slope-4 superstep wavefront, fused dot2 matvecs ----------------
// Per cell: pack own (x,h) into one f16 pair, DPP all-gather the packed dword
// (7 movs), then per gate acc_f32 = sum_j dot2(P_j, {w_ih,w_hh}_j) in two
// independent 4-chains -> 8 independent chains/cell for the in-order wave.
__global__ void
__attribute__((amdgpu_flat_work_group_size(64, 64), amdgpu_waves_per_eu(1, 1)))
slstm_kernel(
    const float* __restrict__ q,
    const float* __restrict__ pWih, const float* __restrict__ pWhh,
    const float* __restrict__ pbih, const float* __restrict__ pbhh,
    const float* __restrict__ vWih, const float* __restrict__ vWhh,
    const float* __restrict__ vbih, const float* __restrict__ vbhh,
    float* __restrict__ out, int U, int N)
{
    const int lane = threadIdx.x;
    const int l = lane >> 3, s = lane & 7;
    const int isV = blockIdx.x;
    const float* Wih = isV ? vWih : pWih;
    const float* Whh = isV ? vWhh : pWhh;
    const float* bi  = isV ? vbih : pbih;
    const float* bh  = isV ? vbhh : pbhh;
    float* ob = out + (size_t)isV * (size_t)N * 64;

    const float cS = -1.4426950408889634f;   // -log2(e): sigmoid rows (i,f,o)
    const float cT =  2.8853900817779268f;   // 2*log2(e): tanh row (g)
    const float invcT = 0.34657359027997264f;

    // DPP butterfly gather order: slot n holds element j = s ^ M[n]
    const int M[8] = {0, 1, 2, 3, 7, 6, 5, 4};

    // packed weights: wg[gate][slot] = {k*Wih[row][j], k*Whh[row][j]}, f16
    half2v wI[8], wF[8], wG[8], wO[8];
    float bI, bF, bG, bO;
    {
        const int r_i = l*32 + 0*8 + s, r_f = l*32 + 1*8 + s;
        const int r_g = l*32 + 2*8 + s, r_o = l*32 + 3*8 + s;
#pragma unroll
        for (int n = 0; n < 8; ++n) {
            const int j = s ^ M[n];
            wI[n] = half2v{(_Float16)(cS * Wih[r_i*8+j]), (_Float16)(cS * Whh[r_i*8+j])};
            wF[n] = half2v{(_Float16)(cS * Wih[r_f*8+j]), (_Float16)(cS * Whh[r_f*8+j])};
            wG[n] = half2v{(_Float16)(cT * Wih[r_g*8+j]), (_Float16)(cT * Whh[r_g*8+j])};
            wO[n] = half2v{(_Float16)(cS * Wih[r_o*8+j]), (_Float16)(cS * Whh[r_o*8+j])};
        }
        bI = cS * (bi[r_i] + bh[r_i]);
        bF = cS * (bi[r_f] + bh[r_f]);
        bG = cT * (bi[r_g] + bh[r_g]);
        bO = cS * (bi[r_o] + bh[r_o]);
    }

    const int axo = ((lane + 56) & 63) << 2;   // pull from lane-8 (group l-1)

    float hp = 0.f, cs = 0.f, Hm = 0.f, Hc = 0.f;   // cs = cT * cell-state
    const bool g7 = (l == 7);
    const float vsel = isV ? 1.0f : 0.0f;

    // cell: pack (x,h), DPP-gather packed, 4 gates x 2 independent dot2 chains,
    // fused inf-safe activations (Eg/Ec clamped: (E-1)*rcp forms).
    auto cell = [&](float xo, float hcur, float cscur, float& h2o, float& cso) {
        const float P0 = __builtin_bit_cast(float, pkrtz(xo, hcur));
        const float P1 = dppf<0xB1>(P0);
        const float P2 = dppf<0x4E>(P0);
        const float P3 = dppf<0x4E>(P1);
        const float P4 = dppf<0x141>(P0);
        const float P5 = dppf<0x141>(P1);
        const float P6 = dppf<0x141>(P2);
        const float P7 = dppf<0x141>(P3);
        float aI = fdot2(P3, wI[3], fdot2(P2, wI[2], fdot2(P1, wI[1], fdot2(P0, wI[0], bI))));
        float uI = fdot2(P7, wI[7], fdot2(P6, wI[6], fdot2(P5, wI[5], fdot2(P4, wI[4], 0.f))));
        float aF = fdot2(P3, wF[3], fdot2(P2, wF[2], fdot2(P1, wF[1], fdot2(P0, wF[0], bF))));
        float uF = fdot2(P7, wF[7], fdot2(P6, wF[6], fdot2(P5, wF[5], fdot2(P4, wF[4], 0.f))));
        float aG = fdot2(P3, wG[3], fdot2(P2, wG[2], fdot2(P1, wG[1], fdot2(P0, wG[0], bG))));
        float uG = fdot2(P7, wG[7], fdot2(P6, wG[6], fdot2(P5, wG[5], fdot2(P4, wG[4], 0.f))));
        float aO = fdot2(P3, wO[3], fdot2(P2, wO[2], fdot2(P1, wO[1], fdot2(P0, wO[0], bO))));
        float uO = fdot2(P7, wO[7], fdot2(P6, wO[6], fdot2(P5, wO[5], fdot2(P4, wO[4], 0.f))));
        const float gI = aI + uI;
        const float gF = aF + uF;
        const float gG = aG + uG;
        const float gO = aO + uO;
        const float Ei = ex2(gI);
        const float Ef = ex2(gF);
        const float Eg = ex2(fminf(gG, 96.f));
        const float Eo = ex2(gO);
        const float fg = frcp(1.f + Ef);
        const float ri = frcp((1.f + Ei) * (1.f + Eg));
        const float igtT = fmaf(cT, Eg, -cT) * ri;     // cT*ig*tanh(g)
        const float cs2 = fmaf(fg, cscur, igtT);
        const float Ec = ex2(fminf(cs2, 96.f));
        const float rh = frcp((1.f + Ec) * (1.f + Eo));
        h2o = (Ec - 1.f) * rh;                          // og * tanh(c)
        cso = cs2;
    };

    // staged inputs (g7 lanes: q-derived; others: y) + pipelined bperm results
    float ys0 = g7 ? q[0*8+s] : 0.f;
    float ys1 = g7 ? q[1*8+s] : 0.f;
    float ys2 = g7 ? q[2*8+s] : 0.f;
    float ys3 = g7 ? q[3*8+s] : 0.f;
    float xq0 = bperm(axo, ys0), xq1 = bperm(axo, ys1);
    float xq2 = bperm(axo, ys2), xq3 = bperm(axo, ys3);

    // ---- startup supersteps D = 0..6 ----
    for (int D = 0; D < 7; ++D) {
        const bool act = (l <= D);
        float h2, cs2;
        cell(xq0, hp, cs, h2, cs2);
        float hr = act ? h2 : hp; float csr = act ? cs2 : cs;
        const float y0 = h2 + xq0;
        cell(xq1, hr, csr, h2, cs2);
        hr = act ? h2 : hr; csr = act ? cs2 : csr;
        const float y1 = h2 + xq1;
        cell(xq2, hr, csr, h2, cs2);
        hr = act ? h2 : hr; csr = act ? cs2 : csr;
        const float y2 = h2 + xq2;
        cell(xq3, hr, csr, h2, cs2);
        hp = act ? h2 : hr; cs = act ? cs2 : csr;
        const float y3 = h2 + xq3;
        const int ub = 4*(D+1);   // positions 4..31 < KK: no V subtract
        ys0 = g7 ? q[(ub+0)*8+s] : y0;
        ys1 = g7 ? q[(ub+1)*8+s] : y1;
        ys2 = g7 ? q[(ub+2)*8+s] : y2;
        ys3 = g7 ? q[(ub+3)*8+s] : y3;
        xq0 = bperm(axo, ys0); xq1 = bperm(axo, ys1);
        xq2 = bperm(axo, ys2); xq3 = bperm(axo, ys3);
    }

    // ---- prefetch ring: 16 slots = 4 supersteps deep; scalar-index loads ----
    float ra[16], rb[16];
#pragma unroll
    for (int p = 0; p < 16; ++p) {
        const int u = 32 + p;                 // 32..47, all valid
        ra[p] = q[u*8 + s];
        int ubb = u - KK; if (ubb < 0) ubb = 0;
        rb[p] = q[ubb*8 + s];
    }

    int upos = 32;            // consume base position (uniform scalar)
    const int Um4 = U - 4;

    auto sstep = [&](int sb, bool boundary, int dlt, bool lastk, int kclip) {
        float h2, cs2;
        float y0, y1, y2, y3;
        if (!boundary) {
            cell(xq0, hp, cs, h2, cs2);
            y0 = h2 + xq0;
            cell(xq1, h2, cs2, h2, cs2);
            y1 = h2 + xq1;
            cell(xq2, h2, cs2, h2, cs2);
            y2 = h2 + xq2;
            cell(xq3, h2, cs2, h2, cs2);
            y3 = h2 + xq3;
            hp = h2; cs = cs2;
        } else {
            const bool act = (!lastk) || (l >= dlt);
            cell(xq0, hp, cs, h2, cs2);
            y0 = h2 + xq0;
            float hr = act ? h2 : hp; float csr = act ? cs2 : cs;
            cell(xq1, hr, csr, h2, cs2);
            y1 = h2 + xq1;
            hr = act ? h2 : hr; csr = act ? cs2 : csr;
            cell(xq2, hr, csr, h2, cs2);
            y2 = h2 + xq2;
            hr = act ? h2 : hr; csr = act ? cs2 : csr;
            cell(xq3, hr, csr, h2, cs2);
            y3 = h2 + xq3;
            const bool bnd = (l == dlt);
            const float HmN = Hm + h2;
            const float HcN = Hc + cs2 * invcT;
            const float hpN = bnd ? HmN : h2;
            const float csN = bnd ? cT * HcN : cs2;
            hp = act ? hpN : hr; cs = act ? csN : csr;
            Hm = bnd ? HmN : Hm;
            Hc = bnd ? HcN : Hc;
            if (bnd) ob[(size_t)kclip * 64 + lane] = HmN;
        }
        // staging from ring (consume-time masks are uniform -> SALU)
        const float qb0 = (upos+0 >= KK) ? rb[sb+0] : 0.f;
        const float qb1 = (upos+1 >= KK) ? rb[sb+1] : 0.f;
        const float qb2 = (upos+2 >= KK) ? rb[sb+2] : 0.f;
        const float qb3 = (upos+3 >= KK) ? rb[sb+3] : 0.f;
        ys0 = g7 ? fmaf(-vsel, qb0, ra[sb+0]) : y0;
        ys1 = g7 ? fmaf(-vsel, qb1, ra[sb+1]) : y1;
        ys2 = g7 ? fmaf(-vsel, qb2, ra[sb+2]) : y2;
        ys3 = g7 ? fmaf(-vsel, qb3, ra[sb+3]) : y3;
        xq0 = bperm(axo, ys0); xq1 = bperm(axo, ys1);
        xq2 = bperm(axo, ys2); xq3 = bperm(axo, ys3);
        // ring refill: scalar-clamped base indices, imm-offset loads
        int ur = upos + 16; if (ur > Um4) ur = Um4;
        int urb = ur - KK;  if (urb < 0) urb = 0;
        const float* pa = q + ur*8 + s;
        const float* pb = q + urb*8 + s;
        ra[sb+0] = pa[0];  ra[sb+1] = pa[8];  ra[sb+2] = pa[16]; ra[sb+3] = pa[24];
        rb[sb+0] = pb[0];  rb[sb+1] = pb[8];  rb[sb+2] = pb[16]; rb[sb+3] = pb[24];
        upos += 4;
    };

    for (int k = 0; k < N; ++k) {
        const bool lastk = (k == N - 1);
        for (int it = 0; it < 65; ++it) {
            sstep(0,  false, 0, false, k);
            sstep(4,  false, 0, false, k);
            sstep(8,  false, 0, false, k);
            sstep(12, false, 0, false, k);
        }
#pragma unroll
        for (int i2 = 0; i2 < 4; ++i2) sstep(i2*4, true, i2,     lastk, k);
#pragma unroll
        for (int i2 = 0; i2 < 4; ++i2) sstep(i2*4, true, 4 + i2, lastk, k);
    }
}

extern "C" void kernel_launch(void* const* d_in, const int* in_sizes, int n_in,
                              void* d_out, int out_size, void* d_ws, size_t ws_size,
                              hipStream_t stream)
{
    const float* vid  = (const float*)d_in[0];
    const float* W1   = (const float*)d_in[1];
    const float* b1   = (const float*)d_in[2];
    const float* gw   = (const float*)d_in[3];
    const float* gb   = (const float*)d_in[4];
    const float* gWih = (const float*)d_in[5];
    const float* gWhh = (const float*)d_in[6];
    const float* gbih = (const float*)d_in[7];
    const float* gbhh = (const float*)d_in[8];
    const float* W2   = (const float*)d_in[9];
    const float* b2   = (const float*)d_in[10];
    const float* vWih = (const float*)d_in[11];
    const float* vWhh = (const float*)d_in[12];
    const float* vbih = (const float*)d_in[13];
    const float* vbhh = (const float*)d_in[14];
    const float* pWih = (const float*)d_in[15];
    const float* pWhh = (const float*)d_in[16];
    const float* pbih = (const float*)d_in[17];
    const float* pbhh = (const float*)d_in[18];

    const int T = in_sizes[0] / (KK * DIN);
    const int N = T / CLIPM;
    const int U = N * CLIPM * KK;
    float* q = (float*)d_ws;   // T*KK*8 floats = 4.4 MB

    grnn_kernel<<<dim3(T), dim3(128), 0, stream>>>(
        vid, W1, b1, gw, gb, gWih, gWhh, gbih, gbhh, W2, b2, q);
    slstm_kernel<<<dim3(2), dim3(64), 0, stream>>>(
        q, pWih, pWhh, pbih, pbhh, vWih, vWhh, vbih, vbhh, (float*)d_out, U, N);
}

// Round 11
// 21754.317 us; speedup vs baseline: 1.3139x; 1.0611x over previous
//
#include <hip/hip_runtime.h>

#define KK 67
#define DIN 4
#define CLIPM 16
#define NEPOCH 5

typedef _Float16 half2v __attribute__((ext_vector_type(2)));
typedef __fp16  fp16v2 __attribute__((ext_vector_type(2)));

__device__ __forceinline__ float ex2(float x) {
#if __has_builtin(__builtin_amdgcn_exp2f)
    return __builtin_amdgcn_exp2f(x);
#else
    return exp2f(x);
#endif
}
__device__ __forceinline__ float frcp(float x) {
#if __has_builtin(__builtin_amdgcn_rcpf)
    return __builtin_amdgcn_rcpf(x);
#else
    return 1.0f / x;
#endif
}
__device__ __forceinline__ float pkrtzf(float a, float b) {
    return __builtin_bit_cast(float, __builtin_amdgcn_cvt_pkrtz(a, b));
}
// v_dot2_f32_f16: d = a.lo*b.lo + a.hi*b.hi + c  (f32 accumulate)
__device__ __forceinline__ float fdot2(float a_bits, half2v b, float c) {
#if __has_builtin(__builtin_amdgcn_fdot2)
    return __builtin_amdgcn_fdot2(__builtin_bit_cast(fp16v2, a_bits),
                                  __builtin_bit_cast(fp16v2, b), c, false);
#else
    half2v a = __builtin_bit_cast(half2v, a_bits);
    return (float)a.x * (float)b.x + (float)a.y * (float)b.y + c;
#endif
}

// DPP lane shuffles. 0xB1=quad xor1, 0x4E=quad xor2, 0x141=row_half_mirror (xor7 in 8-lane half).
template<int CTRL>
__device__ __forceinline__ float dppf(float v) {
    return __int_as_float(__builtin_amdgcn_mov_dpp(__float_as_int(v), CTRL, 0xF, 0xF, false));
}
__device__ __forceinline__ float bperm(int byteaddr, float v) {
    return __int_as_float(__builtin_amdgcn_ds_bpermute(byteaddr, __float_as_int(v)));
}

// ---------------- Phase 1: per-frame GRNN + projections (parallel over T) ----------------
__global__ __launch_bounds__(128) void grnn_kernel(
    const float* __restrict__ vid,
    const float* __restrict__ W1, const float* __restrict__ b1,
    const float* __restrict__ gw, const float* __restrict__ gb,
    const float* __restrict__ gWih, const float* __restrict__ gWhh,
    const float* __restrict__ gbih, const float* __restrict__ gbhh,
    const float* __restrict__ W2, const float* __restrict__ b2,
    float* __restrict__ q)
{
    const int f = blockIdx.x;
    const int t = threadIdx.x;
    const int k = t;
    __shared__ float sWih[256], sWhh[256], sb[32], sW1[32], sb1[8], sW2[64], sb2[8];
    __shared__ float Msum[8];
    for (int i = t; i < 256; i += 128) { sWih[i] = gWih[i]; sWhh[i] = gWhh[i]; }
    if (t < 32) sb[t] = gbih[t] + gbhh[t];
    if (t < 32) sW1[t] = W1[t];
    if (t < 8)  sb1[t] = b1[t];
    if (t < 64) sW2[t] = W2[t];
    if (t < 8)  sb2[t] = b2[t];
    __syncthreads();

    const bool act = (k < KK);
    float R[8], S[8], gwl[8], gbl[8];
    if (act) {
        const float* vp = vid + ((size_t)f * KK + k) * DIN;
        const float v0 = vp[0], v1 = vp[1], v2 = vp[2], v3 = vp[3];
#pragma unroll
        for (int j = 0; j < 8; ++j) {
            R[j] = sb1[j] + sW1[j*4+0]*v0 + sW1[j*4+1]*v1 + sW1[j*4+2]*v2 + sW1[j*4+3]*v3;
            S[j] = 0.0f;
            gwl[j] = gw[k*8 + j];
            gbl[j] = gb[k*8 + j];
        }
    }
    for (int e = 0; e < NEPOCH; ++e) {
        if (t < 8) Msum[t] = 0.0f;
        __syncthreads();
        float per[8];
        if (act) {
#pragma unroll
            for (int j = 0; j < 8; ++j) { per[j] = gwl[j]*S[j] + gbl[j]; atomicAdd(&Msum[j], per[j]); }
        }
        __syncthreads();
        if (act) {
            float M[8];
#pragma unroll
            for (int j = 0; j < 8; ++j) M[j] = Msum[j] - per[j];
            float gv[32];
#pragma unroll
            for (int gg = 0; gg < 32; ++gg) {
                float a = sb[gg];
#pragma unroll
                for (int j = 0; j < 8; ++j)
                    a = fmaf(R[j], sWih[gg*8+j], fmaf(M[j], sWhh[gg*8+j], a));
                gv[gg] = a;
            }
#pragma unroll
            for (int j = 0; j < 8; ++j) {
                float sg_i = frcp(1.f + ex2(-1.4426950408889634f * gv[j]));
                float sg_f = frcp(1.f + ex2(-1.4426950408889634f * gv[8+j]));
                float th_g = 1.f - 2.f * frcp(1.f + ex2(2.8853900817779268f * gv[16+j]));
                float sg_o = frcp(1.f + ex2(-1.4426950408889634f * gv[24+j]));
                float c2 = sg_f * S[j] + sg_i * th_g;
                float h2 = sg_o * (1.f - 2.f * frcp(1.f + ex2(2.8853900817779268f * c2)));
                R[j] += S[j];   // updateRelation uses OLD lastS
                S[j] = h2;
            }
        }
        __syncthreads();
    }
    if (act) {
        float* qp = q + ((size_t)f * KK + k) * 8;
#pragma unroll
        for (int jo = 0; jo < 8; ++jo) {
            float a = sb2[jo];
#pragma unroll
            for (int j = 0; j < 8; ++j) a = fmaf(fmaxf(R[j], 0.0f), sW2[jo*8+j], a);
            qp[jo] = a;
        }
    }
}

// ---------------- Phase 2: slope-4 superstep; x-side presummed, pair-packed h dots ----------------
// Pair packing: P0 = pkrtz(v, dpp_xor1(v)) -> (v_s, v_s^1); P1 = dpp_xor2(P0) ->
// (v_s^2, v_s^3); P2 = mirror(P0) -> (v_s^7, v_s^6); P3 = mirror(P1) -> (v_s^5, v_s^4).
// Weight pair n = {w[j_A(n)], w[j_B(n)]} with JA={0,2,7,5}, JB={1,3,6,4} (xor of s).
__global__ void
__attribute__((amdgpu_flat_work_group_size(64, 64), amdgpu_waves_per_eu(1, 1)))
slstm_kernel(
    const float* __restrict__ q,
    const float* __restrict__ pWih, const float* __restrict__ pWhh,
    const float* __restrict__ pbih, const float* __restrict__ pbhh,
    const float* __restrict__ vWih, const float* __restrict__ vWhh,
    const float* __restrict__ vbih, const float* __restrict__ vbhh,
    float* __restrict__ out, int U, int N)
{
    const int lane = threadIdx.x;
    const int l = lane >> 3, s = lane & 7;
    const int isV = blockIdx.x;
    const float* Wih = isV ? vWih : pWih;
    const float* Whh = isV ? vWhh : pWhh;
    const float* bi  = isV ? vbih : pbih;
    const float* bh  = isV ? vbhh : pbhh;
    float* ob = out + (size_t)isV * (size_t)N * 64;

    const float cS = -1.4426950408889634f;   // -log2(e): sigmoid rows (i,f,o)
    const float cT =  2.8853900817779268f;   // 2*log2(e): tanh row (g)
    const float invcT = 0.34657359027997264f;

    const int JA[4] = {0, 2, 7, 5}, JB[4] = {1, 3, 6, 4};

    half2v wxI[4], wxF[4], wxG[4], wxO[4];   // x-side weight pairs
    half2v whI[4], whF[4], whG[4], whO[4];   // h-side weight pairs
    float bI, bF, bG, bO;
    {
        const int r_i = l*32 + 0*8 + s, r_f = l*32 + 1*8 + s;
        const int r_g = l*32 + 2*8 + s, r_o = l*32 + 3*8 + s;
#pragma unroll
        for (int n = 0; n < 4; ++n) {
            const int jA = s ^ JA[n], jB = s ^ JB[n];
            wxI[n] = half2v{(_Float16)(cS*Wih[r_i*8+jA]), (_Float16)(cS*Wih[r_i*8+jB])};
            wxF[n] = half2v{(_Float16)(cS*Wih[r_f*8+jA]), (_Float16)(cS*Wih[r_f*8+jB])};
            wxG[n] = half2v{(_Float16)(cT*Wih[r_g*8+jA]), (_Float16)(cT*Wih[r_g*8+jB])};
            wxO[n] = half2v{(_Float16)(cS*Wih[r_o*8+jA]), (_Float16)(cS*Wih[r_o*8+jB])};
            whI[n] = half2v{(_Float16)(cS*Whh[r_i*8+jA]), (_Float16)(cS*Whh[r_i*8+jB])};
            whF[n] = half2v{(_Float16)(cS*Whh[r_f*8+jA]), (_Float16)(cS*Whh[r_f*8+jB])};
            whG[n] = half2v{(_Float16)(cT*Whh[r_g*8+jA]), (_Float16)(cT*Whh[r_g*8+jB])};
            whO[n] = half2v{(_Float16)(cS*Whh[r_o*8+jA]), (_Float16)(cS*Whh[r_o*8+jB])};
        }
        bI = cS * (bi[r_i] + bh[r_i]);
        bF = cS * (bi[r_f] + bh[r_f]);
        bG = cT * (bi[r_g] + bh[r_g]);
        bO = cS * (bi[r_o] + bh[r_o]);
    }

    const int axo = ((lane + 56) & 63) << 2;   // pull from lane-8 (group l-1)

    float hp = 0.f, cs = 0.f, Hm = 0.f, Hc = 0.f;   // cs = cT * cell-state
    const bool g7 = (l == 7);
    const float vsel = isV ? 1.0f : 0.0f;

    // x-side gate pre-sums for one position (16 independent dot2)
    auto xg = [&](float xq, float& aI, float& aF, float& aG, float& aO) {
        const float xA = dppf<0xB1>(xq);
        const float X0 = pkrtzf(xq, xA);
        const float X1 = dppf<0x4E>(X0);
        const float X2 = dppf<0x141>(X0);
        const float X3 = dppf<0x141>(X1);
        aI = fdot2(X3, wxI[3], fdot2(X2, wxI[2], fdot2(X1, wxI[1], fdot2(X0, wxI[0], bI))));
        aF = fdot2(X3, wxF[3], fdot2(X2, wxF[2], fdot2(X1, wxF[1], fdot2(X0, wxF[0], bF))));
        aG = fdot2(X3, wxG[3], fdot2(X2, wxG[2], fdot2(X1, wxG[1], fdot2(X0, wxG[0], bG))));
        aO = fdot2(X3, wxO[3], fdot2(X2, wxO[2], fdot2(X1, wxO[1], fdot2(X0, wxO[0], bO))));
    };

    // serial cell: h-gather (pair-packed) + 16 dot2 + inf-safe fused activations
    auto cell = [&](float aI, float aF, float aG, float aO,
                    float hcur, float cscur, float& h2o, float& cso) {
        const float hA = dppf<0xB1>(hcur);
        const float H0 = pkrtzf(hcur, hA);
        const float H1 = dppf<0x4E>(H0);
        const float H2 = dppf<0x141>(H0);
        const float H3 = dppf<0x141>(H1);
        const float gI = fdot2(H3, whI[3], fdot2(H2, whI[2], fdot2(H1, whI[1], fdot2(H0, whI[0], aI))));
        const float gF = fdot2(H3, whF[3], fdot2(H2, whF[2], fdot2(H1, whF[1], fdot2(H0, whF[0], aF))));
        const float gG = fdot2(H3, whG[3], fdot2(H2, whG[2], fdot2(H1, whG[1], fdot2(H0, whG[0], aG))));
        const float gO = fdot2(H3, whO[3], fdot2(H2, whO[2], fdot2(H1, whO[1], fdot2(H0, whO[0], aO))));
        const float Ei = ex2(gI);
        const float Ef = ex2(gF);
        const float Eg = ex2(fminf(gG, 96.f));
        const float Eo = ex2(gO);
        const float fg = frcp(1.f + Ef);
        const float ri = frcp((1.f + Ei) * (1.f + Eg));
        const float igtT = fmaf(cT, Eg, -cT) * ri;     // cT*ig*tanh(g)
        const float cs2 = fmaf(fg, cscur, igtT);
        const float Ec = ex2(fminf(cs2, 96.f));
        const float rh = frcp((1.f + Ec) * (1.f + Eo));
        h2o = (Ec - 1.f) * rh;                          // og * tanh(c)
        cso = cs2;
    };

    // staged inputs (g7 lanes: q-derived; others: y) + pipelined bperm results
    float ys0 = g7 ? q[0*8+s] : 0.f;
    float ys1 = g7 ? q[1*8+s] : 0.f;
    float ys2 = g7 ? q[2*8+s] : 0.f;
    float ys3 = g7 ? q[3*8+s] : 0.f;
    float xq0 = bperm(axo, ys0), xq1 = bperm(axo, ys1);
    float xq2 = bperm(axo, ys2), xq3 = bperm(axo, ys3);

    // ---- startup supersteps D = 0..6 ----
    for (int D = 0; D < 7; ++D) {
        float aI0,aF0,aG0,aO0, aI1,aF1,aG1,aO1, aI2,aF2,aG2,aO2, aI3,aF3,aG3,aO3;
        xg(xq0, aI0,aF0,aG0,aO0); xg(xq1, aI1,aF1,aG1,aO1);
        xg(xq2, aI2,aF2,aG2,aO2); xg(xq3, aI3,aF3,aG3,aO3);
        const bool act = (l <= D);
        float h2, cs2;
        cell(aI0,aF0,aG0,aO0, hp, cs, h2, cs2);
        float hr = act ? h2 : hp; float csr = act ? cs2 : cs;
        const float y0 = h2 + xq0;
        cell(aI1,aF1,aG1,aO1, hr, csr, h2, cs2);
        hr = act ? h2 : hr; csr = act ? cs2 : csr;
        const float y1 = h2 + xq1;
        cell(aI2,aF2,aG2,aO2, hr, csr, h2, cs2);
        hr = act ? h2 : hr; csr = act ? cs2 : csr;
        const float y2 = h2 + xq2;
        cell(aI3,aF3,aG3,aO3, hr, csr, h2, cs2);
        hp = act ? h2 : hr; cs = act ? cs2 : csr;
        const float y3 = h2 + xq3;
        const int ub = 4*(D+1);   // positions 4..31 < KK: no V subtract
        ys0 = g7 ? q[(ub+0)*8+s] : y0;
        ys1 = g7 ? q[(ub+1)*8+s] : y1;
        ys2 = g7 ? q[(ub+2)*8+s] : y2;
        ys3 = g7 ? q[(ub+3)*8+s] : y3;
        xq0 = bperm(axo, ys0); xq1 = bperm(axo, ys1);
        xq2 = bperm(axo, ys2); xq3 = bperm(axo, ys3);
    }

    // ---- prefetch ring: 16 slots = 4 supersteps deep ----
    float ra[16], rb[16];
#pragma unroll
    for (int p = 0; p < 16; ++p) {
        const int u = 32 + p;                 // 32..47, all valid
        ra[p] = q[u*8 + s];
        int ubb = u - KK; if (ubb < 0) ubb = 0;
        rb[p] = q[ubb*8 + s];
    }

    int upos = 32;            // consume base position (uniform scalar)
    const int Um4 = U - 4;

    auto sstep = [&](int sb, bool boundary, int dlt, bool lastk, int kclip) {
        float aI0,aF0,aG0,aO0, aI1,aF1,aG1,aO1, aI2,aF2,aG2,aO2, aI3,aF3,aG3,aO3;
        xg(xq0, aI0,aF0,aG0,aO0); xg(xq1, aI1,aF1,aG1,aO1);
        xg(xq2, aI2,aF2,aG2,aO2); xg(xq3, aI3,aF3,aG3,aO3);
        float h2, cs2;
        float y0, y1, y2, y3;
        if (!boundary) {
            cell(aI0,aF0,aG0,aO0, hp, cs, h2, cs2);
            y0 = h2 + xq0;
            cell(aI1,aF1,aG1,aO1, h2, cs2, h2, cs2);
            y1 = h2 + xq1;
            cell(aI2,aF2,aG2,aO2, h2, cs2, h2, cs2);
            y2 = h2 + xq2;
            cell(aI3,aF3,aG3,aO3, h2, cs2, h2, cs2);
            y3 = h2 + xq3;
            hp = h2; cs = cs2;
        } else {
            const bool act = (!lastk) || (l >= dlt);
            cell(aI0,aF0,aG0,aO0, hp, cs, h2, cs2);
            y0 = h2 + xq0;
            float hr = act ? h2 : hp; float csr = act ? cs2 : cs;
            cell(aI1,aF1,aG1,aO1, hr, csr, h2, cs2);
            y1 = h2 + xq1;
            hr = act ? h2 : hr; csr = act ? cs2 : csr;
            cell(aI2,aF2,aG2,aO2, hr, csr, h2, cs2);
            y2 = h2 + xq2;
            hr = act ? h2 : hr; csr = act ? cs2 : csr;
            cell(aI3,aF3,aG3,aO3, hr, csr, h2, cs2);
            y3 = h2 + xq3;
            const bool bnd = (l == dlt);
            const float HmN = Hm + h2;
            const float HcN = Hc + cs2 * invcT;
            const float hpN = bnd ? HmN : h2;
            const float csN = bnd ? cT * HcN : cs2;
            hp = act ? hpN : hr; cs = act ? csN : csr;
            Hm = bnd ? HmN : Hm;
            Hc = bnd ? HcN : Hc;
            if (bnd) ob[(size_t)kclip * 64 + lane] = HmN;
        }
        // staging from ring
        const float qb0 = (upos+0 >= KK) ? rb[sb+0] : 0.f;
        const float qb1 = (upos+1 >= KK) ? rb[sb+1] : 0.f;
        const float qb2 = (upos+2 >= KK) ? rb[sb+2] : 0.f;
        const float qb3 = (upos+3 >= KK) ? rb[sb+3] : 0.f;
        ys0 = g7 ? fmaf(-vsel, qb0, ra[sb+0]) : y0;
        ys1 = g7 ? fmaf(-vsel, qb1, ra[sb+1]) : y1;
        ys2 = g7 ? fmaf(-vsel, qb2, ra[sb+2]) : y2;
        ys3 = g7 ? fmaf(-vsel, qb3, ra[sb+3]) : y3;
        xq0 = bperm(axo, ys0); xq1 = bperm(axo, ys1);
        xq2 = bperm(axo, ys2); xq3 = bperm(axo, ys3);
        // ring refill: scalar-clamped base indices, imm-offset loads
        int ur = upos + 16; if (ur > Um4) ur = Um4;
        int urb = ur - KK;  if (urb < 0) urb = 0;
        const float* pa = q + ur*8 + s;
        const float* pb = q + urb*8 + s;
        ra[sb+0] = pa[0];  ra[sb+1] = pa[8];  ra[sb+2] = pa[16]; ra[sb+3] = pa[24];
        rb[sb+0] = pb[0];  rb[sb+1] = pb[8];  rb[sb+2] = pb[16]; rb[sb+3] = pb[24];
        upos += 4;
    };

    for (int k = 0; k < N; ++k) {
        const bool lastk = (k == N - 1);
        for (int it = 0; it < 65; ++it) {
            sstep(0,  false, 0, false, k);
            sstep(4,  false, 0, false, k);
            sstep(8,  false, 0, false, k);
            sstep(12, false, 0, false, k);
        }
#pragma unroll
        for (int i2 = 0; i2 < 4; ++i2) sstep(i2*4, true, i2,     lastk, k);
#pragma unroll
        for (int i2 = 0; i2 < 4; ++i2) sstep(i2*4, true, 4 + i2, lastk, k);
    }
}

extern "C" void kernel_launch(void* const* d_in, const int* in_sizes, int n_in,
                              void* d_out, int out_size, void* d_ws, size_t ws_size,
                              hipStream_t stream)
{
    const float* vid  = (const float*)d_in[0];
    const float* W1   = (const float*)d_in[1];
    const float* b1   = (const float*)d_in[2];
    const float* gw   = (const float*)d_in[3];
    const float* gb   = (const float*)d_in[4];
    const float* gWih = (const float*)d_in[5];
    const float* gWhh = (const float*)d_in[6];
    const float* gbih = (const float*)d_in[7];
    const float* gbhh = (const float*)d_in[8];
    const float* W2   = (const float*)d_in[9];
    const float* b2   = (const float*)d_in[10];
    const float* vWih = (const float*)d_in[11];
    const float* vWhh = (const float*)d_in[12];
    const float* vbih = (const float*)d_in[13];
    const float* vbhh = (const float*)d_in[14];
    const float* pWih = (const float*)d_in[15];
    const float* pWhh = (const float*)d_in[16];
    const float* pbih = (const float*)d_in[17];
    const float* pbhh = (const float*)d_in[18];

    const int T = in_sizes[0] / (KK * DIN);
    const int N = T / CLIPM;
    const int U = N * CLIPM * KK;
    float* q = (float*)d_ws;   // T*KK*8 floats = 4.4 MB

    grnn_kernel<<<dim3(T), dim3(128), 0, stream>>>(
        vid, W1, b1, gw, gb, gWih, gWhh, gbih, gbhh, W2, b2, q);
    slstm_kernel<<<dim3(2), dim3(64), 0, stream>>>(
        q, pWih, pWhh, pbih, pbhh, vWih, vWhh, vbih, vbhh, (float*)d_out, U, N);
}